// Round 15
// baseline (553.663 us; speedup 1.0000x reference)
//
#include <hip/hip_runtime.h>
#include <cstdint>
#include <cstddef>

#define NV 4096
#define NE 8192
#define INV 128
#define OUTV 128
#define INE 64

#define BK 64
#define NT (NE / BK)        // 128 K-tiles
#define HALF_B 16384        // 128 rows x 64 bf16 x 2B
#define LDS_BYTES (9 * HALF_B)  // 5 A-slots + 4 B-slots = 144 KiB
#define NPAIR 136           // 16x16 tile grid, upper triangle incl diag

typedef __bf16 bf16x8 __attribute__((ext_vector_type(8)));
typedef float f32x4 __attribute__((ext_vector_type(4)));

__device__ __forceinline__ uint16_t f2bf(float x) {
  uint32_t u = __builtin_bit_cast(uint32_t, x);
  u += 0x7fff + ((u >> 16) & 1);
  return (uint16_t)(u >> 16);
}
__device__ __forceinline__ float bf2f(uint16_t u) {
  uint32_t v = ((uint32_t)u) << 16;
  return __builtin_bit_cast(float, v);
}

// d[e] = dot(H_e[e, :64], p[:64]); one wave per row.  Also zeroes the work counter.
__global__ void k_diag(const float* __restrict__ He, const float* __restrict__ p,
                       float* __restrict__ d, unsigned int* __restrict__ cnt) {
  if (blockIdx.x == 0 && threadIdx.x == 0 && cnt) *cnt = 0u;
  int lane = threadIdx.x & 63;
  int wid = threadIdx.x >> 6;
  int row = blockIdx.x * 4 + wid;
  float v = He[(size_t)row * INE + lane] * p[lane];
#pragma unroll
  for (int off = 32; off; off >>= 1) v += __shfl_xor(v, off);
  if (lane == 0) d[row] = v;
}

// Abf = bf16(T * d[col]), Bbf = bf16(T)   (both [NV][NE] row-major)
__global__ void k_prep(const float4* __restrict__ T4, const float4* __restrict__ d4,
                       ushort4* __restrict__ A4, ushort4* __restrict__ B4) {
  const size_t total = (size_t)NV * NE / 4;
  size_t stride = (size_t)gridDim.x * blockDim.x;
  for (size_t i = (size_t)blockIdx.x * blockDim.x + threadIdx.x; i < total; i += stride) {
    float4 t = T4[i];
    float4 dv = d4[i & (NE / 4 - 1)];
    ushort4 a, b;
    b.x = f2bf(t.x); b.y = f2bf(t.y); b.z = f2bf(t.z); b.w = f2bf(t.w);
    a.x = f2bf(t.x * dv.x); a.y = f2bf(t.y * dv.y);
    a.z = f2bf(t.z * dv.z); a.w = f2bf(t.w * dv.w);
    A4[i] = a;
    B4[i] = b;
  }
}

// XT[n][m] = bf16( sum_k H_v[m][k] * W[k][n] )   (X^T, [OUTV][NV])
__global__ void k_xw(const float* __restrict__ Hv, const float* __restrict__ W,
                     uint16_t* __restrict__ XT) {
  __shared__ float row[INV];
  int m = blockIdx.x;
  int n = threadIdx.x;  // 128 threads
  row[n] = Hv[(size_t)m * INV + n];
  __syncthreads();
  float acc = 0.f;
#pragma unroll 8
  for (int k = 0; k < INV; ++k) acc += row[k] * W[k * OUTV + n];
  XT[(size_t)n * NV + m] = f2bf(acc);
}

__device__ __forceinline__ void gload16(const char* src, char* ldst) {
  __builtin_amdgcn_global_load_lds(
      (const __attribute__((address_space(1))) uint32_t*)src,
      (__attribute__((address_space(3))) uint32_t*)ldst, 16, 0, 0);
}

// ---- SYMMETRIC gemm1: triangle pair (a,b), K-split, bf16 partial out ----
// mode 0: 408 pieces, all pairs split-3 (slot = pair*3+piece)
// mode 1: 512 pieces, 0..95 = pairs 104..135 split-3 (BIG first),
//         96..511 = pairs 0..103 split-4 (32 tiles)
// cnt != nullptr: persistent work-stealing (launch 256 blocks); else idx=blockIdx.
__global__ __launch_bounds__(512, 2) void k_gemm1s(const uint16_t* __restrict__ A,
                                                   const uint16_t* __restrict__ B,
                                                   uint16_t* __restrict__ part,
                                                   int mode, int nblk,
                                                   unsigned int* __restrict__ cnt) {
  extern __shared__ char smem[];
  __shared__ int s_idx;
  char* Aslot = smem;                 // 5 x HALF_B
  char* Bslot = smem + 5 * HALF_B;    // 4 x HALF_B

  const int tid = threadIdx.x;
  const int lane = tid & 63, wid = tid >> 6;
  const int wr = wid >> 2, wc = wid & 3;
  const int lr = lane & 15, lk = lane >> 4;
  const int bcol0 = (wc & 1) * 64;

  const int swz0 = ((lk) ^ (lr & 7)) << 4;
  const int swz1 = ((4 + lk) ^ (lr & 7)) << 4;
  const int pA0 = lr * 128 + swz0;
  const int pA1 = lr * 128 + swz1;
  const int pB0 = (bcol0 + lr) * 128 + swz0;
  const int pB1 = (bcol0 + lr) * 128 + swz1;

  const int srow = tid >> 3;
  const int sslot = (tid & 7) ^ (srow & 7);
  const int soff0 = srow * 16384 + sslot * 16;
  const int soff1 = soff0 + 64 * 16384;
  const int ld0 = tid * 16;
  const int ld1 = tid * 16 + 8192;

  for (;;) {
    int idx;
    if (cnt) {
      if (tid == 0) s_idx = (int)atomicAdd(cnt, 1u);
      __syncthreads();            // broadcast + drains prior piece's stores
      idx = s_idx;
      if (idx >= nblk) return;
    } else {
      idx = blockIdx.x;
    }

    int pair, k0t, nt;
    if (mode == 0) {
      pair = idx / 3;
      int piece = idx - pair * 3;
      k0t = piece * 43;
      nt = (piece < 2) ? 43 : 42;
    } else if (idx < 96) {
      int t3 = idx / 3;
      int piece = idx - t3 * 3;
      pair = 104 + t3;
      k0t = piece * 43;
      nt = (piece < 2) ? 43 : 42;
    } else {
      int q = idx - 96;
      pair = q >> 2;
      int piece = q & 3;
      k0t = piece * 32;
      nt = 32;
    }

    int qq = pair, a = 0;
    while (qq >= 16 - a) { qq -= 16 - a; ++a; }
    const int b = a + qq;
    const int kb0 = k0t * 128;

    const char* Abase = (const char*)A + (size_t)(a * 256) * 16384;
    const char* Bbase = (const char*)B + (size_t)(b * 256) * 16384;

    f32x4 acc[8][4] = {};
    bf16x8 af[4][2], af2[4][2], bfr[2][2], bfr2[2][2];

    // prologue: first tile all halves + A0(+1)
    gload16(Abase + kb0 + soff0, Aslot + ld0);
    gload16(Abase + kb0 + soff1, Aslot + ld1);
    gload16(Abase + 2097152 + kb0 + soff0, Aslot + HALF_B + ld0);
    gload16(Abase + 2097152 + kb0 + soff1, Aslot + HALF_B + ld1);
    gload16(Bbase + kb0 + soff0, Bslot + ld0);
    gload16(Bbase + kb0 + soff1, Bslot + ld1);
    gload16(Bbase + 2097152 + kb0 + soff0, Bslot + HALF_B + ld0);
    gload16(Bbase + 2097152 + kb0 + soff1, Bslot + HALF_B + ld1);
    gload16(Abase + kb0 + 128 + soff0, Aslot + 2 * HALF_B + ld0);
    gload16(Abase + kb0 + 128 + soff1, Aslot + 2 * HALF_B + ld1);
    asm volatile("s_waitcnt vmcnt(2)" ::: "memory");
    asm volatile("s_barrier" ::: "memory");

    int sA = 0;
    int sB = 0;
    for (int t = 0; t < nt; ++t) {
      const char* aB = Aslot + (((sA + wr) >= 5) ? (sA + wr - 5) : (sA + wr)) * HALF_B;
      const char* bB = Bslot + ((sB + (wc >> 1)) & 3) * HALF_B;
      const char* aK0 = aB + pA0;
      const char* aK1 = aB + pA1;
      const char* bK0 = bB + pB0;
      const char* bK1 = bB + pB1;
      const int k1 = kb0 + (t + 1) * 128;
      const int k2 = kb0 + (t + 2) * 128;

      // P1: Q00 operands; stage A1,B0,B1 of t+1
#pragma unroll
      for (int m = 0; m < 4; ++m) {
        af[m][0] = *(const bf16x8*)(aK0 + m * 2048);
        af[m][1] = *(const bf16x8*)(aK1 + m * 2048);
      }
#pragma unroll
      for (int n = 0; n < 2; ++n) {
        bfr[n][0] = *(const bf16x8*)(bK0 + n * 2048);
        bfr[n][1] = *(const bf16x8*)(bK1 + n * 2048);
      }
      if (t + 1 < nt) {
        int s1 = sA + 3; if (s1 >= 5) s1 -= 5;
        char* dA1 = Aslot + s1 * HALF_B;
        gload16(Abase + 2097152 + k1 + soff0, dA1 + ld0);
        gload16(Abase + 2097152 + k1 + soff1, dA1 + ld1);
        char* dB0 = Bslot + ((sB + 2) & 3) * HALF_B;
        gload16(Bbase + k1 + soff0, dB0 + ld0);
        gload16(Bbase + k1 + soff1, dB0 + ld1);
        char* dB1 = Bslot + ((sB + 3) & 3) * HALF_B;
        gload16(Bbase + 2097152 + k1 + soff0, dB1 + ld0);
        gload16(Bbase + 2097152 + k1 + soff1, dB1 + ld1);
      }
#pragma unroll
      for (int m = 0; m < 4; ++m)
#pragma unroll
        for (int n = 0; n < 2; ++n)
#pragma unroll
          for (int kk = 0; kk < 2; ++kk)
            acc[m][n] = __builtin_amdgcn_mfma_f32_16x16x32_bf16(af[m][kk], bfr[n][kk], acc[m][n], 0, 0, 0);

      // P2: Q01 B-operand; stage A0(t+2)
#pragma unroll
      for (int n = 0; n < 2; ++n) {
        bfr2[n][0] = *(const bf16x8*)(bK0 + 4096 + n * 2048);
        bfr2[n][1] = *(const bf16x8*)(bK1 + 4096 + n * 2048);
      }
      if (t + 2 < nt) {
        int s2 = sA + 4; if (s2 >= 5) s2 -= 5;
        char* dA0 = Aslot + s2 * HALF_B;
        gload16(Abase + k2 + soff0, dA0 + ld0);
        gload16(Abase + k2 + soff1, dA0 + ld1);
      }
#pragma unroll
      for (int m = 0; m < 4; ++m)
#pragma unroll
        for (int n = 0; n < 2; ++n)
#pragma unroll
          for (int kk = 0; kk < 2; ++kk)
            acc[m][2 + n] = __builtin_amdgcn_mfma_f32_16x16x32_bf16(af[m][kk], bfr2[n][kk], acc[m][2 + n], 0, 0, 0);

      // P3: Q11 A-operand
#pragma unroll
      for (int m = 0; m < 4; ++m) {
        af2[m][0] = *(const bf16x8*)(aK0 + 8192 + m * 2048);
        af2[m][1] = *(const bf16x8*)(aK1 + 8192 + m * 2048);
      }
#pragma unroll
      for (int m = 0; m < 4; ++m)
#pragma unroll
        for (int n = 0; n < 2; ++n)
#pragma unroll
          for (int kk = 0; kk < 2; ++kk)
            acc[4 + m][2 + n] = __builtin_amdgcn_mfma_f32_16x16x32_bf16(af2[m][kk], bfr2[n][kk], acc[4 + m][2 + n], 0, 0, 0);

      // P4
#pragma unroll
      for (int m = 0; m < 4; ++m)
#pragma unroll
        for (int n = 0; n < 2; ++n)
#pragma unroll
          for (int kk = 0; kk < 2; ++kk)
            acc[4 + m][n] = __builtin_amdgcn_mfma_f32_16x16x32_bf16(af2[m][kk], bfr[n][kk], acc[4 + m][n], 0, 0, 0);

      if (t + 2 < nt) {
        asm volatile("s_waitcnt vmcnt(2)" ::: "memory");
      } else {
        asm volatile("s_waitcnt vmcnt(0)" ::: "memory");
      }
      asm volatile("s_barrier" ::: "memory");

      sA += 2; if (sA >= 5) sA -= 5;
      sB ^= 2;
    }

    // store bf16 partial [256][256] at slot = idx
    uint16_t* myp = part + (size_t)idx * 65536;
#pragma unroll
    for (int m = 0; m < 8; ++m) {
      int rowb = wr * 128 + m * 16 + lk * 4;
#pragma unroll
      for (int n = 0; n < 4; ++n) {
        int col = wc * 64 + n * 16 + lr;
#pragma unroll
        for (int r = 0; r < 4; ++r)
          myp[(rowb + r) * 256 + col] = f2bf(acc[m][n][r]);
      }
    }

    if (!cnt) return;
  }
}

// reduce partials, diag->1, * adj_v, write direct + transposed blocks
__global__ __launch_bounds__(256) void k_m1red(const uint16_t* __restrict__ part,
                                               const float* __restrict__ adj_v,
                                               uint16_t* __restrict__ adjA,
                                               int mode) {
  __shared__ float ls[64][65];
  int tq = blockIdx.x;
  int SI = 0;
  while (tq >= 64 - SI) { tq -= 64 - SI; ++SI; }
  int SJ = SI + tq;
  const int R0 = SI * 64, C0 = SJ * 64;
  const int a = SI >> 2, b = SJ >> 2;            // a<=b guaranteed
  const int q = 16 * a - (a * (a - 1)) / 2 + (b - a);

  int sbase, scnt;
  if (mode == 0) { sbase = q * 3; scnt = 3; }
  else if (q < 104) { sbase = 96 + q * 4; scnt = 4; }
  else { sbase = (q - 104) * 3; scnt = 3; }

  const size_t off0 = (size_t)(R0 & 255) * 256 + (C0 & 255);
  const int tx = threadIdx.x & 63, ty = threadIdx.x >> 6;  // ty 0..3
  float vals[16];
#pragma unroll
  for (int yy = 0; yy < 16; ++yy) {
    int x = ty * 16 + yy;
    size_t off = off0 + x * 256 + tx;
    float s = 0.f;
    for (int i = 0; i < scnt; ++i)
      s += bf2f(part[(size_t)(sbase + i) * 65536 + off]);
    vals[yy] = s;
    ls[x][tx] = s;
  }
  __syncthreads();
#pragma unroll
  for (int yy = 0; yy < 16; ++yy) {
    int x = ty * 16 + yy;
    int gr = R0 + x, gc = C0 + tx;
    float v = (gr == gc) ? 1.0f : vals[yy];
    adjA[(size_t)gr * NV + gc] = f2bf(v * adj_v[(size_t)gr * NV + gc]);
  }
  if (SI != SJ) {
#pragma unroll
    for (int yy = 0; yy < 16; ++yy) {
      int x = ty * 16 + yy;
      float tv = ls[tx][x];
      int gr = C0 + x, gc = R0 + tx;
      adjA[(size_t)gr * NV + gc] = f2bf(tv * adj_v[(size_t)gr * NV + gc]);
    }
  }
}

// ---- FALLBACK full gemm1 (r12, proven) ----
__global__ __launch_bounds__(512, 2) void k_gemm1(const uint16_t* __restrict__ A,
                                                  const uint16_t* __restrict__ B,
                                                  const float* __restrict__ adj_v,
                                                  uint16_t* __restrict__ adjA) {
  extern __shared__ char smem[];
  char* Aslot = smem;
  char* Bslot = smem + 5 * HALF_B;

  const int tid = threadIdx.x;
  const int lane = tid & 63, wid = tid >> 6;
  const int wr = wid >> 2, wc = wid & 3;
  const int lr = lane & 15, lk = lane >> 4;
  const int bcol0 = (wc & 1) * 64;

  int bid = blockIdx.x;
  int xcd = bid & 7, cid = bid >> 3;
  int bi = (xcd >> 1) * 4 + (cid >> 3);
  int bj = (xcd & 1) * 8 + (cid & 7);

  const int swz0 = ((lk) ^ (lr & 7)) << 4;
  const int swz1 = ((4 + lk) ^ (lr & 7)) << 4;
  const int pA0 = lr * 128 + swz0;
  const int pA1 = lr * 128 + swz1;
  const int pB0 = (bcol0 + lr) * 128 + swz0;
  const int pB1 = (bcol0 + lr) * 128 + swz1;

  const int srow = tid >> 3;
  const int sslot = (tid & 7) ^ (srow & 7);
  const int soff0 = srow * 16384 + sslot * 16;
  const int soff1 = soff0 + 64 * 16384;
  const char* Abase = (const char*)A + (size_t)(bi * 256) * 16384;
  const char* Bbase = (const char*)B + (size_t)(bj * 256) * 16384;
  const int ld0 = tid * 16;
  const int ld1 = tid * 16 + 8192;

  f32x4 acc[8][4] = {};
  bf16x8 af[4][2], af2[4][2], bfr[2][2], bfr2[2][2];

  gload16(Abase + soff0, Aslot + ld0);
  gload16(Abase + soff1, Aslot + ld1);
  gload16(Abase + 2097152 + soff0, Aslot + HALF_B + ld0);
  gload16(Abase + 2097152 + soff1, Aslot + HALF_B + ld1);
  gload16(Bbase + soff0, Bslot + ld0);
  gload16(Bbase + soff1, Bslot + ld1);
  gload16(Bbase + 2097152 + soff0, Bslot + HALF_B + ld0);
  gload16(Bbase + 2097152 + soff1, Bslot + HALF_B + ld1);
  gload16(Abase + 128 + soff0, Aslot + 2 * HALF_B + ld0);
  gload16(Abase + 128 + soff1, Aslot + 2 * HALF_B + ld1);
  asm volatile("s_waitcnt vmcnt(2)" ::: "memory");
  asm volatile("s_barrier" ::: "memory");

  int sA = 0, sB = 0;
  for (int t = 0; t < NT; ++t) {
    const char* aB = Aslot + (((sA + wr) >= 5) ? (sA + wr - 5) : (sA + wr)) * HALF_B;
    const char* bB = Bslot + ((sB + (wc >> 1)) & 3) * HALF_B;
    const char* aK0 = aB + pA0;
    const char* aK1 = aB + pA1;
    const char* bK0 = bB + pB0;
    const char* bK1 = bB + pB1;
    const int k1 = (t + 1) * 128;
    const int k2 = (t + 2) * 128;

#pragma unroll
    for (int m = 0; m < 4; ++m) {
      af[m][0] = *(const bf16x8*)(aK0 + m * 2048);
      af[m][1] = *(const bf16x8*)(aK1 + m * 2048);
    }
#pragma unroll
    for (int n = 0; n < 2; ++n) {
      bfr[n][0] = *(const bf16x8*)(bK0 + n * 2048);
      bfr[n][1] = *(const bf16x8*)(bK1 + n * 2048);
    }
    if (t + 1 < NT) {
      int s1 = sA + 3; if (s1 >= 5) s1 -= 5;
      char* dA1 = Aslot + s1 * HALF_B;
      gload16(Abase + 2097152 + k1 + soff0, dA1 + ld0);
      gload16(Abase + 2097152 + k1 + soff1, dA1 + ld1);
      char* dB0 = Bslot + ((sB + 2) & 3) * HALF_B;
      gload16(Bbase + k1 + soff0, dB0 + ld0);
      gload16(Bbase + k1 + soff1, dB0 + ld1);
      char* dB1 = Bslot + ((sB + 3) & 3) * HALF_B;
      gload16(Bbase + 2097152 + k1 + soff0, dB1 + ld0);
      gload16(Bbase + 2097152 + k1 + soff1, dB1 + ld1);
    }
#pragma unroll
    for (int m = 0; m < 4; ++m)
#pragma unroll
      for (int n = 0; n < 2; ++n)
#pragma unroll
        for (int kk = 0; kk < 2; ++kk)
          acc[m][n] = __builtin_amdgcn_mfma_f32_16x16x32_bf16(af[m][kk], bfr[n][kk], acc[m][n], 0, 0, 0);

#pragma unroll
    for (int n = 0; n < 2; ++n) {
      bfr2[n][0] = *(const bf16x8*)(bK0 + 4096 + n * 2048);
      bfr2[n][1] = *(const bf16x8*)(bK1 + 4096 + n * 2048);
    }
    if (t + 2 < NT) {
      int s2 = sA + 4; if (s2 >= 5) s2 -= 5;
      char* dA0 = Aslot + s2 * HALF_B;
      gload16(Abase + k2 + soff0, dA0 + ld0);
      gload16(Abase + k2 + soff1, dA0 + ld1);
    }
#pragma unroll
    for (int m = 0; m < 4; ++m)
#pragma unroll
      for (int n = 0; n < 2; ++n)
#pragma unroll
        for (int kk = 0; kk < 2; ++kk)
          acc[m][2 + n] = __builtin_amdgcn_mfma_f32_16x16x32_bf16(af[m][kk], bfr2[n][kk], acc[m][2 + n], 0, 0, 0);

#pragma unroll
    for (int m = 0; m < 4; ++m) {
      af2[m][0] = *(const bf16x8*)(aK0 + 8192 + m * 2048);
      af2[m][1] = *(const bf16x8*)(aK1 + 8192 + m * 2048);
    }
#pragma unroll
    for (int m = 0; m < 4; ++m)
#pragma unroll
      for (int n = 0; n < 2; ++n)
#pragma unroll
        for (int kk = 0; kk < 2; ++kk)
          acc[4 + m][2 + n] = __builtin_amdgcn_mfma_f32_16x16x32_bf16(af2[m][kk], bfr2[n][kk], acc[4 + m][2 + n], 0, 0, 0);

#pragma unroll
    for (int m = 0; m < 4; ++m)
#pragma unroll
      for (int n = 0; n < 2; ++n)
#pragma unroll
        for (int kk = 0; kk < 2; ++kk)
          acc[4 + m][n] = __builtin_amdgcn_mfma_f32_16x16x32_bf16(af2[m][kk], bfr[n][kk], acc[4 + m][n], 0, 0, 0);

    if (t + 2 < NT) {
      asm volatile("s_waitcnt vmcnt(2)" ::: "memory");
    } else {
      asm volatile("s_waitcnt vmcnt(0)" ::: "memory");
    }
    asm volatile("s_barrier" ::: "memory");

    sA += 2; if (sA >= 5) sA -= 5;
    sB ^= 2;
  }

#pragma unroll
  for (int m = 0; m < 8; ++m) {
    int grow0 = bi * 256 + wr * 128 + m * 16 + lk * 4;
#pragma unroll
    for (int n = 0; n < 4; ++n) {
      int gcol = bj * 256 + wc * 64 + n * 16 + lr;
#pragma unroll
      for (int r = 0; r < 4; ++r) {
        int grow = grow0 + r;
        float v = acc[m][n][r];
        if (grow == gcol) v = 1.0f;
        adjA[(size_t)grow * NV + gcol] = f2bf(v * adj_v[(size_t)grow * NV + gcol]);
      }
    }
  }
}

// partial = adjA[bi*128..][krange] @ XT^T[krange]  (K-split 8 -> 256 blocks)
__global__ __launch_bounds__(256) void k_gemm2p(const uint16_t* __restrict__ A,
                                                const uint16_t* __restrict__ B,
                                                float* __restrict__ part) {
  __shared__ __align__(16) uint16_t As[128 * 32];
  __shared__ __align__(16) uint16_t Bs[128 * 32];
  const int tid = threadIdx.x;
  const int wid = tid >> 6, lane = tid & 63;
  const int wr = wid >> 1, wc = wid & 1;
  const int ks = blockIdx.x & 7;
  const int bi = blockIdx.x >> 3;
  const int lr = lane & 15, lk = lane >> 4;

  f32x4 acc[4][4] = {};

  for (int kt = ks * 16; kt < ks * 16 + 16; ++kt) {
#pragma unroll
    for (int i = 0; i < 2; ++i) {
      int o = (wid * 2 + i) * 1024 + lane * 16;
      int row = o >> 6, kb = o & 63;
      const char* ga = (const char*)A + ((size_t)(bi * 128 + row) * NV + kt * 32) * 2 + kb;
      const char* gb = (const char*)B + ((size_t)row * NV + kt * 32) * 2 + kb;
      __builtin_amdgcn_global_load_lds(
          (const __attribute__((address_space(1))) uint32_t*)ga,
          (__attribute__((address_space(3))) uint32_t*)((char*)As + (wid * 2 + i) * 1024),
          16, 0, 0);
      __builtin_amdgcn_global_load_lds(
          (const __attribute__((address_space(1))) uint32_t*)gb,
          (__attribute__((address_space(3))) uint32_t*)((char*)Bs + (wid * 2 + i) * 1024),
          16, 0, 0);
    }
    __syncthreads();
    bf16x8 af[4], bfr[4];
#pragma unroll
    for (int m = 0; m < 4; ++m)
      af[m] = *(const bf16x8*)&As[(wr * 64 + m * 16 + lr) * 32 + lk * 8];
#pragma unroll
    for (int n = 0; n < 4; ++n)
      bfr[n] = *(const bf16x8*)&Bs[(wc * 64 + n * 16 + lr) * 32 + lk * 8];
#pragma unroll
    for (int m = 0; m < 4; ++m)
#pragma unroll
      for (int n = 0; n < 4; ++n)
        acc[m][n] = __builtin_amdgcn_mfma_f32_16x16x32_bf16(af[m], bfr[n], acc[m][n], 0, 0, 0);
    __syncthreads();
  }

  float* my = part + (size_t)ks * NV * OUTV;
#pragma unroll
  for (int m = 0; m < 4; ++m) {
    int grow0 = bi * 128 + wr * 64 + m * 16 + lk * 4;
#pragma unroll
    for (int n = 0; n < 4; ++n) {
      int gcol = wc * 64 + n * 16 + lr;
#pragma unroll
      for (int r = 0; r < 4; ++r)
        my[(size_t)(grow0 + r) * OUTV + gcol] = acc[m][n][r];
    }
  }
}

// out = sum_ks part[ks] + bias
__global__ void k_gemm2r(const float4* __restrict__ part, const float* __restrict__ bias,
                         float4* __restrict__ out) {
  int i = blockIdx.x * 256 + threadIdx.x;
  float4 s = part[i];
#pragma unroll
  for (int ks = 1; ks < 8; ++ks) {
    float4 q = part[(size_t)ks * (NV * OUTV / 4) + i];
    s.x += q.x; s.y += q.y; s.z += q.z; s.w += q.w;
  }
  float4 b = ((const float4*)bias)[i & 31];
  s.x += b.x; s.y += b.y; s.z += b.z; s.w += b.w;
  out[i] = s;
}

extern "C" void kernel_launch(void* const* d_in, const int* in_sizes, int n_in,
                              void* d_out, int out_size, void* d_ws, size_t ws_size,
                              hipStream_t stream) {
  const float* Hv = (const float*)d_in[0];
  const float* He = (const float*)d_in[1];
  // d_in[2] = adj_e — UNUSED by the reference
  const float* adj_v = (const float*)d_in[3];
  const float* T = (const float*)d_in[4];
  const float* W = (const float*)d_in[5];
  const float* bias = (const float*)d_in[6];
  const float* p = (const float*)d_in[7];
  float* out = (float*)d_out;

  char* ws = (char*)d_ws;
  float* dvec = (float*)ws;                                   // 32 KB
  uint16_t* XT = (uint16_t*)(ws + 32768);                     // 1 MB
  uint16_t* Abf = (uint16_t*)(ws + 32768 + (1u << 20));       // 64 MB
  uint16_t* Bbf = Abf + (size_t)NV * NE;                      // 64 MB

  const size_t base = 32768 + (1u << 20) + 2 * (size_t)NV * NE * 2;
  const size_t need_mix = base + (size_t)512 * 65536 * 2 + 4096;  // mode 1 + counter
  const size_t need_u3 = base + (size_t)408 * 65536 * 2 + 4096;   // mode 0 + counter

  static int lds_attr_set = 0;
  if (!lds_attr_set) {
    hipFuncSetAttribute((const void*)k_gemm1,
                        hipFuncAttributeMaxDynamicSharedMemorySize, LDS_BYTES);
    hipFuncSetAttribute((const void*)k_gemm1s,
                        hipFuncAttributeMaxDynamicSharedMemorySize, LDS_BYTES);
    lds_attr_set = 1;
  }

  if (ws_size >= need_u3) {
    const int mode = (ws_size >= need_mix) ? 1 : 0;
    const int nblk = mode ? 512 : 408;
    uint16_t* part16 = (uint16_t*)(ws + base);
    unsigned int* cnt = (unsigned int*)(ws + base + (size_t)nblk * 65536 * 2);
    uint16_t* adjA = Abf;            // overlay: Abf dead after k_gemm1s
    float* part2 = (float*)Bbf;      // overlay: Bbf dead after k_gemm1s

    k_diag<<<NE / 4, 256, 0, stream>>>(He, p, dvec, cnt);
    k_prep<<<2048, 256, 0, stream>>>((const float4*)T, (const float4*)dvec,
                                     (ushort4*)Abf, (ushort4*)Bbf);
    k_xw<<<NV, INV, 0, stream>>>(Hv, W, XT);
    k_gemm1s<<<256, 512, LDS_BYTES, stream>>>(Abf, Bbf, part16, mode, nblk, cnt);
    k_m1red<<<2080, 256, 0, stream>>>(part16, adj_v, adjA, mode);
    k_gemm2p<<<256, 256, 0, stream>>>(adjA, XT, part2);
    k_gemm2r<<<NV * OUTV / 4 / 256, 256, 0, stream>>>((const float4*)part2, bias, (float4*)out);
  } else {
    uint16_t* adjA = Bbf + (size_t)NV * NE;                   // r12 layout
    float* part2 = (float*)Abf;
    k_diag<<<NE / 4, 256, 0, stream>>>(He, p, dvec, nullptr);
    k_prep<<<2048, 256, 0, stream>>>((const float4*)T, (const float4*)dvec,
                                     (ushort4*)Abf, (ushort4*)Bbf);
    k_xw<<<NV, INV, 0, stream>>>(Hv, W, XT);
    k_gemm1<<<256, 512, LDS_BYTES, stream>>>(Abf, Bbf, adj_v, adjA);
    k_gemm2p<<<256, 256, 0, stream>>>(adjA, XT, part2);
    k_gemm2r<<<NV * OUTV / 4 / 256, 256, 0, stream>>>((const float4*)part2, bias, (float4*)out);
  }

  hipMemcpyAsync(out + (size_t)NV * OUTV, He, (size_t)NE * INE * sizeof(float),
                 hipMemcpyDeviceToDevice, stream);
}

// Round 16
// 265.815 us; speedup vs baseline: 2.0829x; 2.0829x over previous
//
#include <hip/hip_runtime.h>
#include <cstdint>
#include <cstddef>

#define NV 4096
#define NE 8192
#define INV 128
#define OUTV 128
#define INE 64

#define BK 64
#define NT (NE / BK)        // 128 K-tiles
#define HALF_B 16384        // 128 rows x 64 bf16 x 2B
#define LDS_BYTES (9 * HALF_B)  // 5 A-slots + 4 B-slots = 144 KiB
#define NPAIR 136           // 16x16 tile grid, upper triangle incl diag

typedef __bf16 bf16x8 __attribute__((ext_vector_type(8)));
typedef float f32x4 __attribute__((ext_vector_type(4)));

__device__ __forceinline__ uint16_t f2bf(float x) {
  uint32_t u = __builtin_bit_cast(uint32_t, x);
  u += 0x7fff + ((u >> 16) & 1);
  return (uint16_t)(u >> 16);
}
__device__ __forceinline__ float bf2f(uint16_t u) {
  uint32_t v = ((uint32_t)u) << 16;
  return __builtin_bit_cast(float, v);
}

// d[e] = dot(H_e[e, :64], p[:64]); one wave per row
__global__ void k_diag(const float* __restrict__ He, const float* __restrict__ p,
                       float* __restrict__ d) {
  int lane = threadIdx.x & 63;
  int wid = threadIdx.x >> 6;
  int row = blockIdx.x * 4 + wid;
  float v = He[(size_t)row * INE + lane] * p[lane];
#pragma unroll
  for (int off = 32; off; off >>= 1) v += __shfl_xor(v, off);
  if (lane == 0) d[row] = v;
}

// Abf = bf16(T * d[col]), Bbf = bf16(T)   (both [NV][NE] row-major)
__global__ void k_prep(const float4* __restrict__ T4, const float4* __restrict__ d4,
                       ushort4* __restrict__ A4, ushort4* __restrict__ B4) {
  const size_t total = (size_t)NV * NE / 4;
  size_t stride = (size_t)gridDim.x * blockDim.x;
  for (size_t i = (size_t)blockIdx.x * blockDim.x + threadIdx.x; i < total; i += stride) {
    float4 t = T4[i];
    float4 dv = d4[i & (NE / 4 - 1)];
    ushort4 a, b;
    b.x = f2bf(t.x); b.y = f2bf(t.y); b.z = f2bf(t.z); b.w = f2bf(t.w);
    a.x = f2bf(t.x * dv.x); a.y = f2bf(t.y * dv.y);
    a.z = f2bf(t.z * dv.z); a.w = f2bf(t.w * dv.w);
    A4[i] = a;
    B4[i] = b;
  }
}

// XT[n][m] = bf16( sum_k H_v[m][k] * W[k][n] )   (X^T, [OUTV][NV])
__global__ void k_xw(const float* __restrict__ Hv, const float* __restrict__ W,
                     uint16_t* __restrict__ XT) {
  __shared__ float row[INV];
  int m = blockIdx.x;
  int n = threadIdx.x;  // 128 threads
  row[n] = Hv[(size_t)m * INV + n];
  __syncthreads();
  float acc = 0.f;
#pragma unroll 8
  for (int k = 0; k < INV; ++k) acc += row[k] * W[k * OUTV + n];
  XT[(size_t)n * NV + m] = f2bf(acc);
}

__device__ __forceinline__ void gload16(const char* src, char* ldst) {
  __builtin_amdgcn_global_load_lds(
      (const __attribute__((address_space(1))) uint32_t*)src,
      (__attribute__((address_space(3))) uint32_t*)ldst, 16, 0, 0);
}

// ---- SYMMETRIC gemm1: triangle pair (a,b), K-split, bf16 partial out ----
// mode 0: 408 blocks, all pairs split-3 (slot = pair*3+piece)
// mode 1: 512 blocks, blocks 0..95 = pairs 104..135 split-3 (BIG, dispatched
//         first), blocks 96..511 = pairs 0..103 split-4 (32 tiles)
__global__ __launch_bounds__(512, 2) void k_gemm1s(const uint16_t* __restrict__ A,
                                                   const uint16_t* __restrict__ B,
                                                   uint16_t* __restrict__ part,
                                                   int mode) {
  extern __shared__ char smem[];
  char* Aslot = smem;                 // 5 x HALF_B
  char* Bslot = smem + 5 * HALF_B;    // 4 x HALF_B

  const int tid = threadIdx.x;
  const int lane = tid & 63, wid = tid >> 6;
  const int wr = wid >> 2, wc = wid & 3;
  const int lr = lane & 15, lk = lane >> 4;
  const int bcol0 = (wc & 1) * 64;

  const int idx = blockIdx.x;
  int pair, k0t, nt;
  if (mode == 0) {
    pair = idx / 3;
    int piece = idx - pair * 3;
    k0t = piece * 43;
    nt = (piece < 2) ? 43 : 42;
  } else if (idx < 96) {
    int t3 = idx / 3;
    int piece = idx - t3 * 3;
    pair = 104 + t3;
    k0t = piece * 43;
    nt = (piece < 2) ? 43 : 42;
  } else {
    int q = idx - 96;
    pair = q >> 2;
    int piece = q & 3;
    k0t = piece * 32;
    nt = 32;
  }

  int qq = pair, a = 0;
  while (qq >= 16 - a) { qq -= 16 - a; ++a; }
  const int b = a + qq;
  const int kb0 = k0t * 128;           // byte offset of first K-tile

  const int swz0 = ((lk) ^ (lr & 7)) << 4;
  const int swz1 = ((4 + lk) ^ (lr & 7)) << 4;
  const int pA0 = lr * 128 + swz0;
  const int pA1 = lr * 128 + swz1;
  const int pB0 = (bcol0 + lr) * 128 + swz0;
  const int pB1 = (bcol0 + lr) * 128 + swz1;

  const int srow = tid >> 3;
  const int sslot = (tid & 7) ^ (srow & 7);
  const int soff0 = srow * 16384 + sslot * 16;
  const int soff1 = soff0 + 64 * 16384;
  const char* Abase = (const char*)A + (size_t)(a * 256) * 16384;
  const char* Bbase = (const char*)B + (size_t)(b * 256) * 16384;
  const int ld0 = tid * 16;
  const int ld1 = tid * 16 + 8192;

  f32x4 acc[8][4] = {};
  bf16x8 af[4][2], af2[4][2], bfr[2][2], bfr2[2][2];

  // prologue: first tile all halves + A0(+1)
  gload16(Abase + kb0 + soff0, Aslot + ld0);
  gload16(Abase + kb0 + soff1, Aslot + ld1);
  gload16(Abase + 2097152 + kb0 + soff0, Aslot + HALF_B + ld0);
  gload16(Abase + 2097152 + kb0 + soff1, Aslot + HALF_B + ld1);
  gload16(Bbase + kb0 + soff0, Bslot + ld0);
  gload16(Bbase + kb0 + soff1, Bslot + ld1);
  gload16(Bbase + 2097152 + kb0 + soff0, Bslot + HALF_B + ld0);
  gload16(Bbase + 2097152 + kb0 + soff1, Bslot + HALF_B + ld1);
  gload16(Abase + kb0 + 128 + soff0, Aslot + 2 * HALF_B + ld0);
  gload16(Abase + kb0 + 128 + soff1, Aslot + 2 * HALF_B + ld1);
  asm volatile("s_waitcnt vmcnt(2)" ::: "memory");
  asm volatile("s_barrier" ::: "memory");

  int sA = 0;
  int sB = 0;
  for (int t = 0; t < nt; ++t) {
    const char* aB = Aslot + (((sA + wr) >= 5) ? (sA + wr - 5) : (sA + wr)) * HALF_B;
    const char* bB = Bslot + ((sB + (wc >> 1)) & 3) * HALF_B;
    const char* aK0 = aB + pA0;
    const char* aK1 = aB + pA1;
    const char* bK0 = bB + pB0;
    const char* bK1 = bB + pB1;
    const int k1 = kb0 + (t + 1) * 128;
    const int k2 = kb0 + (t + 2) * 128;

    // P1: Q00 operands; stage A1,B0,B1 of t+1
#pragma unroll
    for (int m = 0; m < 4; ++m) {
      af[m][0] = *(const bf16x8*)(aK0 + m * 2048);
      af[m][1] = *(const bf16x8*)(aK1 + m * 2048);
    }
#pragma unroll
    for (int n = 0; n < 2; ++n) {
      bfr[n][0] = *(const bf16x8*)(bK0 + n * 2048);
      bfr[n][1] = *(const bf16x8*)(bK1 + n * 2048);
    }
    if (t + 1 < nt) {
      int s1 = sA + 3; if (s1 >= 5) s1 -= 5;
      char* dA1 = Aslot + s1 * HALF_B;
      gload16(Abase + 2097152 + k1 + soff0, dA1 + ld0);
      gload16(Abase + 2097152 + k1 + soff1, dA1 + ld1);
      char* dB0 = Bslot + ((sB + 2) & 3) * HALF_B;
      gload16(Bbase + k1 + soff0, dB0 + ld0);
      gload16(Bbase + k1 + soff1, dB0 + ld1);
      char* dB1 = Bslot + ((sB + 3) & 3) * HALF_B;
      gload16(Bbase + 2097152 + k1 + soff0, dB1 + ld0);
      gload16(Bbase + 2097152 + k1 + soff1, dB1 + ld1);
    }
#pragma unroll
    for (int m = 0; m < 4; ++m)
#pragma unroll
      for (int n = 0; n < 2; ++n)
#pragma unroll
        for (int kk = 0; kk < 2; ++kk)
          acc[m][n] = __builtin_amdgcn_mfma_f32_16x16x32_bf16(af[m][kk], bfr[n][kk], acc[m][n], 0, 0, 0);

    // P2: Q01 B-operand; stage A0(t+2)
#pragma unroll
    for (int n = 0; n < 2; ++n) {
      bfr2[n][0] = *(const bf16x8*)(bK0 + 4096 + n * 2048);
      bfr2[n][1] = *(const bf16x8*)(bK1 + 4096 + n * 2048);
    }
    if (t + 2 < nt) {
      int s2 = sA + 4; if (s2 >= 5) s2 -= 5;
      char* dA0 = Aslot + s2 * HALF_B;
      gload16(Abase + k2 + soff0, dA0 + ld0);
      gload16(Abase + k2 + soff1, dA0 + ld1);
    }
#pragma unroll
    for (int m = 0; m < 4; ++m)
#pragma unroll
      for (int n = 0; n < 2; ++n)
#pragma unroll
        for (int kk = 0; kk < 2; ++kk)
          acc[m][2 + n] = __builtin_amdgcn_mfma_f32_16x16x32_bf16(af[m][kk], bfr2[n][kk], acc[m][2 + n], 0, 0, 0);

    // P3: Q11 A-operand
#pragma unroll
    for (int m = 0; m < 4; ++m) {
      af2[m][0] = *(const bf16x8*)(aK0 + 8192 + m * 2048);
      af2[m][1] = *(const bf16x8*)(aK1 + 8192 + m * 2048);
    }
#pragma unroll
    for (int m = 0; m < 4; ++m)
#pragma unroll
      for (int n = 0; n < 2; ++n)
#pragma unroll
        for (int kk = 0; kk < 2; ++kk)
          acc[4 + m][2 + n] = __builtin_amdgcn_mfma_f32_16x16x32_bf16(af2[m][kk], bfr2[n][kk], acc[4 + m][2 + n], 0, 0, 0);

    // P4
#pragma unroll
    for (int m = 0; m < 4; ++m)
#pragma unroll
      for (int n = 0; n < 2; ++n)
#pragma unroll
        for (int kk = 0; kk < 2; ++kk)
          acc[4 + m][n] = __builtin_amdgcn_mfma_f32_16x16x32_bf16(af2[m][kk], bfr[n][kk], acc[4 + m][n], 0, 0, 0);

    if (t + 2 < nt) {
      asm volatile("s_waitcnt vmcnt(2)" ::: "memory");
    } else {
      asm volatile("s_waitcnt vmcnt(0)" ::: "memory");
    }
    asm volatile("s_barrier" ::: "memory");

    sA += 2; if (sA >= 5) sA -= 5;
    sB ^= 2;
  }

  // store bf16 partial [256][256] at slot = blockIdx
  uint16_t* myp = part + (size_t)idx * 65536;
#pragma unroll
  for (int m = 0; m < 8; ++m) {
    int rowb = wr * 128 + m * 16 + lk * 4;
#pragma unroll
    for (int n = 0; n < 4; ++n) {
      int col = wc * 64 + n * 16 + lr;
#pragma unroll
      for (int r = 0; r < 4; ++r)
        myp[(rowb + r) * 256 + col] = f2bf(acc[m][n][r]);
    }
  }
}

// reduce partials, diag->1, * adj_v, write direct + transposed blocks
__global__ __launch_bounds__(256) void k_m1red(const uint16_t* __restrict__ part,
                                               const float* __restrict__ adj_v,
                                               uint16_t* __restrict__ adjA,
                                               int mode) {
  __shared__ float ls[64][65];
  // decode 64-grain triangle block (SI<=SJ), 2080 total
  int tq = blockIdx.x;
  int SI = 0;
  while (tq >= 64 - SI) { tq -= 64 - SI; ++SI; }
  int SJ = SI + tq;
  const int R0 = SI * 64, C0 = SJ * 64;
  const int a = SI >> 2, b = SJ >> 2;            // a<=b guaranteed
  const int q = 16 * a - (a * (a - 1)) / 2 + (b - a);

  int sbase, scnt;
  if (mode == 0) { sbase = q * 3; scnt = 3; }
  else if (q < 104) { sbase = 96 + q * 4; scnt = 4; }
  else { sbase = (q - 104) * 3; scnt = 3; }

  const size_t off0 = (size_t)(R0 & 255) * 256 + (C0 & 255);
  const int tx = threadIdx.x & 63, ty = threadIdx.x >> 6;  // ty 0..3
  float vals[16];
#pragma unroll
  for (int yy = 0; yy < 16; ++yy) {
    int x = ty * 16 + yy;
    size_t off = off0 + x * 256 + tx;
    float s = 0.f;
    for (int i = 0; i < scnt; ++i)
      s += bf2f(part[(size_t)(sbase + i) * 65536 + off]);
    vals[yy] = s;
    ls[x][tx] = s;
  }
  __syncthreads();
  // direct block (R0.., C0..)
#pragma unroll
  for (int yy = 0; yy < 16; ++yy) {
    int x = ty * 16 + yy;
    int gr = R0 + x, gc = C0 + tx;
    float v = (gr == gc) ? 1.0f : vals[yy];
    adjA[(size_t)gr * NV + gc] = f2bf(v * adj_v[(size_t)gr * NV + gc]);
  }
  // transposed block (C0.., R0..)
  if (SI != SJ) {
#pragma unroll
    for (int yy = 0; yy < 16; ++yy) {
      int x = ty * 16 + yy;
      float tv = ls[tx][x];
      int gr = C0 + x, gc = R0 + tx;
      adjA[(size_t)gr * NV + gc] = f2bf(tv * adj_v[(size_t)gr * NV + gc]);
    }
  }
}

// ---- FALLBACK full gemm1 (r12, proven) ----
__global__ __launch_bounds__(512, 2) void k_gemm1(const uint16_t* __restrict__ A,
                                                  const uint16_t* __restrict__ B,
                                                  const float* __restrict__ adj_v,
                                                  uint16_t* __restrict__ adjA) {
  extern __shared__ char smem[];
  char* Aslot = smem;
  char* Bslot = smem + 5 * HALF_B;

  const int tid = threadIdx.x;
  const int lane = tid & 63, wid = tid >> 6;
  const int wr = wid >> 2, wc = wid & 3;
  const int lr = lane & 15, lk = lane >> 4;
  const int bcol0 = (wc & 1) * 64;

  int bid = blockIdx.x;
  int xcd = bid & 7, cid = bid >> 3;
  int bi = (xcd >> 1) * 4 + (cid >> 3);
  int bj = (xcd & 1) * 8 + (cid & 7);

  const int swz0 = ((lk) ^ (lr & 7)) << 4;
  const int swz1 = ((4 + lk) ^ (lr & 7)) << 4;
  const int pA0 = lr * 128 + swz0;
  const int pA1 = lr * 128 + swz1;
  const int pB0 = (bcol0 + lr) * 128 + swz0;
  const int pB1 = (bcol0 + lr) * 128 + swz1;

  const int srow = tid >> 3;
  const int sslot = (tid & 7) ^ (srow & 7);
  const int soff0 = srow * 16384 + sslot * 16;
  const int soff1 = soff0 + 64 * 16384;
  const char* Abase = (const char*)A + (size_t)(bi * 256) * 16384;
  const char* Bbase = (const char*)B + (size_t)(bj * 256) * 16384;
  const int ld0 = tid * 16;
  const int ld1 = tid * 16 + 8192;

  f32x4 acc[8][4] = {};
  bf16x8 af[4][2], af2[4][2], bfr[2][2], bfr2[2][2];

  gload16(Abase + soff0, Aslot + ld0);
  gload16(Abase + soff1, Aslot + ld1);
  gload16(Abase + 2097152 + soff0, Aslot + HALF_B + ld0);
  gload16(Abase + 2097152 + soff1, Aslot + HALF_B + ld1);
  gload16(Bbase + soff0, Bslot + ld0);
  gload16(Bbase + soff1, Bslot + ld1);
  gload16(Bbase + 2097152 + soff0, Bslot + HALF_B + ld0);
  gload16(Bbase + 2097152 + soff1, Bslot + HALF_B + ld1);
  gload16(Abase + 128 + soff0, Aslot + 2 * HALF_B + ld0);
  gload16(Abase + 128 + soff1, Aslot + 2 * HALF_B + ld1);
  asm volatile("s_waitcnt vmcnt(2)" ::: "memory");
  asm volatile("s_barrier" ::: "memory");

  int sA = 0, sB = 0;
  for (int t = 0; t < NT; ++t) {
    const char* aB = Aslot + (((sA + wr) >= 5) ? (sA + wr - 5) : (sA + wr)) * HALF_B;
    const char* bB = Bslot + ((sB + (wc >> 1)) & 3) * HALF_B;
    const char* aK0 = aB + pA0;
    const char* aK1 = aB + pA1;
    const char* bK0 = bB + pB0;
    const char* bK1 = bB + pB1;
    const int k1 = (t + 1) * 128;
    const int k2 = (t + 2) * 128;

#pragma unroll
    for (int m = 0; m < 4; ++m) {
      af[m][0] = *(const bf16x8*)(aK0 + m * 2048);
      af[m][1] = *(const bf16x8*)(aK1 + m * 2048);
    }
#pragma unroll
    for (int n = 0; n < 2; ++n) {
      bfr[n][0] = *(const bf16x8*)(bK0 + n * 2048);
      bfr[n][1] = *(const bf16x8*)(bK1 + n * 2048);
    }
    if (t + 1 < NT) {
      int s1 = sA + 3; if (s1 >= 5) s1 -= 5;
      char* dA1 = Aslot + s1 * HALF_B;
      gload16(Abase + 2097152 + k1 + soff0, dA1 + ld0);
      gload16(Abase + 2097152 + k1 + soff1, dA1 + ld1);
      char* dB0 = Bslot + ((sB + 2) & 3) * HALF_B;
      gload16(Bbase + k1 + soff0, dB0 + ld0);
      gload16(Bbase + k1 + soff1, dB0 + ld1);
      char* dB1 = Bslot + ((sB + 3) & 3) * HALF_B;
      gload16(Bbase + 2097152 + k1 + soff0, dB1 + ld0);
      gload16(Bbase + 2097152 + k1 + soff1, dB1 + ld1);
    }
#pragma unroll
    for (int m = 0; m < 4; ++m)
#pragma unroll
      for (int n = 0; n < 2; ++n)
#pragma unroll
        for (int kk = 0; kk < 2; ++kk)
          acc[m][n] = __builtin_amdgcn_mfma_f32_16x16x32_bf16(af[m][kk], bfr[n][kk], acc[m][n], 0, 0, 0);

#pragma unroll
    for (int n = 0; n < 2; ++n) {
      bfr2[n][0] = *(const bf16x8*)(bK0 + 4096 + n * 2048);
      bfr2[n][1] = *(const bf16x8*)(bK1 + 4096 + n * 2048);
    }
    if (t + 2 < NT) {
      int s2 = sA + 4; if (s2 >= 5) s2 -= 5;
      char* dA0 = Aslot + s2 * HALF_B;
      gload16(Abase + k2 + soff0, dA0 + ld0);
      gload16(Abase + k2 + soff1, dA0 + ld1);
    }
#pragma unroll
    for (int m = 0; m < 4; ++m)
#pragma unroll
      for (int n = 0; n < 2; ++n)
#pragma unroll
        for (int kk = 0; kk < 2; ++kk)
          acc[m][2 + n] = __builtin_amdgcn_mfma_f32_16x16x32_bf16(af[m][kk], bfr2[n][kk], acc[m][2 + n], 0, 0, 0);

#pragma unroll
    for (int m = 0; m < 4; ++m) {
      af2[m][0] = *(const bf16x8*)(aK0 + 8192 + m * 2048);
      af2[m][1] = *(const bf16x8*)(aK1 + 8192 + m * 2048);
    }
#pragma unroll
    for (int m = 0; m < 4; ++m)
#pragma unroll
      for (int n = 0; n < 2; ++n)
#pragma unroll
        for (int kk = 0; kk < 2; ++kk)
          acc[4 + m][2 + n] = __builtin_amdgcn_mfma_f32_16x16x32_bf16(af2[m][kk], bfr2[n][kk], acc[4 + m][2 + n], 0, 0, 0);

#pragma unroll
    for (int m = 0; m < 4; ++m)
#pragma unroll
      for (int n = 0; n < 2; ++n)
#pragma unroll
        for (int kk = 0; kk < 2; ++kk)
          acc[4 + m][n] = __builtin_amdgcn_mfma_f32_16x16x32_bf16(af2[m][kk], bfr[n][kk], acc[4 + m][n], 0, 0, 0);

    if (t + 2 < NT) {
      asm volatile("s_waitcnt vmcnt(2)" ::: "memory");
    } else {
      asm volatile("s_waitcnt vmcnt(0)" ::: "memory");
    }
    asm volatile("s_barrier" ::: "memory");

    sA += 2; if (sA >= 5) sA -= 5;
    sB ^= 2;
  }

#pragma unroll
  for (int m = 0; m < 8; ++m) {
    int grow0 = bi * 256 + wr * 128 + m * 16 + lk * 4;
#pragma unroll
    for (int n = 0; n < 4; ++n) {
      int gcol = bj * 256 + wc * 64 + n * 16 + lr;
#pragma unroll
      for (int r = 0; r < 4; ++r) {
        int grow = grow0 + r;
        float v = acc[m][n][r];
        if (grow == gcol) v = 1.0f;
        adjA[(size_t)grow * NV + gcol] = f2bf(v * adj_v[(size_t)grow * NV + gcol]);
      }
    }
  }
}

// partial = adjA[bi*128..][krange] @ XT^T[krange]  (K-split 8 -> 256 blocks)
__global__ __launch_bounds__(256) void k_gemm2p(const uint16_t* __restrict__ A,
                                                const uint16_t* __restrict__ B,
                                                float* __restrict__ part) {
  __shared__ __align__(16) uint16_t As[128 * 32];
  __shared__ __align__(16) uint16_t Bs[128 * 32];
  const int tid = threadIdx.x;
  const int wid = tid >> 6, lane = tid & 63;
  const int wr = wid >> 1, wc = wid & 1;
  const int ks = blockIdx.x & 7;
  const int bi = blockIdx.x >> 3;
  const int lr = lane & 15, lk = lane >> 4;

  f32x4 acc[4][4] = {};

  for (int kt = ks * 16; kt < ks * 16 + 16; ++kt) {
#pragma unroll
    for (int i = 0; i < 2; ++i) {
      int o = (wid * 2 + i) * 1024 + lane * 16;
      int row = o >> 6, kb = o & 63;
      const char* ga = (const char*)A + ((size_t)(bi * 128 + row) * NV + kt * 32) * 2 + kb;
      const char* gb = (const char*)B + ((size_t)row * NV + kt * 32) * 2 + kb;
      __builtin_amdgcn_global_load_lds(
          (const __attribute__((address_space(1))) uint32_t*)ga,
          (__attribute__((address_space(3))) uint32_t*)((char*)As + (wid * 2 + i) * 1024),
          16, 0, 0);
      __builtin_amdgcn_global_load_lds(
          (const __attribute__((address_space(1))) uint32_t*)gb,
          (__attribute__((address_space(3))) uint32_t*)((char*)Bs + (wid * 2 + i) * 1024),
          16, 0, 0);
    }
    __syncthreads();
    bf16x8 af[4], bfr[4];
#pragma unroll
    for (int m = 0; m < 4; ++m)
      af[m] = *(const bf16x8*)&As[(wr * 64 + m * 16 + lr) * 32 + lk * 8];
#pragma unroll
    for (int n = 0; n < 4; ++n)
      bfr[n] = *(const bf16x8*)&Bs[(wc * 64 + n * 16 + lr) * 32 + lk * 8];
#pragma unroll
    for (int m = 0; m < 4; ++m)
#pragma unroll
      for (int n = 0; n < 4; ++n)
        acc[m][n] = __builtin_amdgcn_mfma_f32_16x16x32_bf16(af[m], bfr[n], acc[m][n], 0, 0, 0);
    __syncthreads();
  }

  float* my = part + (size_t)ks * NV * OUTV;
#pragma unroll
  for (int m = 0; m < 4; ++m) {
    int grow0 = bi * 128 + wr * 64 + m * 16 + lk * 4;
#pragma unroll
    for (int n = 0; n < 4; ++n) {
      int gcol = wc * 64 + n * 16 + lr;
#pragma unroll
      for (int r = 0; r < 4; ++r)
        my[(size_t)(grow0 + r) * OUTV + gcol] = acc[m][n][r];
    }
  }
}

// out = sum_ks part[ks] + bias
__global__ void k_gemm2r(const float4* __restrict__ part, const float* __restrict__ bias,
                         float4* __restrict__ out) {
  int i = blockIdx.x * 256 + threadIdx.x;
  float4 s = part[i];
#pragma unroll
  for (int ks = 1; ks < 8; ++ks) {
    float4 q = part[(size_t)ks * (NV * OUTV / 4) + i];
    s.x += q.x; s.y += q.y; s.z += q.z; s.w += q.w;
  }
  float4 b = ((const float4*)bias)[i & 31];
  s.x += b.x; s.y += b.y; s.z += b.z; s.w += b.w;
  out[i] = s;
}

extern "C" void kernel_launch(void* const* d_in, const int* in_sizes, int n_in,
                              void* d_out, int out_size, void* d_ws, size_t ws_size,
                              hipStream_t stream) {
  const float* Hv = (const float*)d_in[0];
  const float* He = (const float*)d_in[1];
  // d_in[2] = adj_e — UNUSED by the reference
  const float* adj_v = (const float*)d_in[3];
  const float* T = (const float*)d_in[4];
  const float* W = (const float*)d_in[5];
  const float* bias = (const float*)d_in[6];
  const float* p = (const float*)d_in[7];
  float* out = (float*)d_out;

  char* ws = (char*)d_ws;
  float* dvec = (float*)ws;                                   // 32 KB
  uint16_t* XT = (uint16_t*)(ws + 32768);                     // 1 MB
  uint16_t* Abf = (uint16_t*)(ws + 32768 + (1u << 20));       // 64 MB
  uint16_t* Bbf = Abf + (size_t)NV * NE;                      // 64 MB

  const size_t base = 32768 + (1u << 20) + 2 * (size_t)NV * NE * 2;
  const size_t need_mix = base + (size_t)512 * 65536 * 2;   // mode 1
  const size_t need_u3 = base + (size_t)408 * 65536 * 2;    // mode 0

  static int lds_attr_set = 0;
  if (!lds_attr_set) {
    hipFuncSetAttribute((const void*)k_gemm1,
                        hipFuncAttributeMaxDynamicSharedMemorySize, LDS_BYTES);
    hipFuncSetAttribute((const void*)k_gemm1s,
                        hipFuncAttributeMaxDynamicSharedMemorySize, LDS_BYTES);
    lds_attr_set = 1;
  }

  k_diag<<<NE / 4, 256, 0, stream>>>(He, p, dvec);
  k_prep<<<2048, 256, 0, stream>>>((const float4*)T, (const float4*)dvec,
                                   (ushort4*)Abf, (ushort4*)Bbf);
  k_xw<<<NV, INV, 0, stream>>>(Hv, W, XT);

  if (ws_size >= need_u3) {
    const int mode = (ws_size >= need_mix) ? 1 : 0;
    const int nblk = mode ? 512 : 408;
    uint16_t* part16 = (uint16_t*)(ws + base);
    uint16_t* adjA = Abf;            // overlay: Abf dead after k_gemm1s
    float* part2 = (float*)Bbf;      // overlay: Bbf dead after k_gemm1s
    k_gemm1s<<<nblk, 512, LDS_BYTES, stream>>>(Abf, Bbf, part16, mode);
    k_m1red<<<2080, 256, 0, stream>>>(part16, adj_v, adjA, mode);
    k_gemm2p<<<256, 256, 0, stream>>>(adjA, XT, part2);
    k_gemm2r<<<NV * OUTV / 4 / 256, 256, 0, stream>>>((const float4*)part2, bias, (float4*)out);
  } else {
    uint16_t* adjA = Bbf + (size_t)NV * NE;                   // r12 layout
    float* part2 = (float*)Abf;
    k_gemm1<<<256, 512, LDS_BYTES, stream>>>(Abf, Bbf, adj_v, adjA);
    k_gemm2p<<<256, 256, 0, stream>>>(adjA, XT, part2);
    k_gemm2r<<<NV * OUTV / 4 / 256, 256, 0, stream>>>((const float4*)part2, bias, (float4*)out);
  }

  hipMemcpyAsync(out + (size_t)NV * OUTV, He, (size_t)NE * INE * sizeof(float),
                 hipMemcpyDeviceToDevice, stream);
}